// Round 6
// baseline (206.220 us; speedup 1.0000x reference)
//
#include <hip/hip_runtime.h>
#include <stdint.h>

typedef unsigned short u16;
typedef __attribute__((ext_vector_type(8))) __bf16 bf16x8;
typedef __attribute__((ext_vector_type(4))) float f32x4;
typedef __attribute__((ext_vector_type(4))) u16 u16x4;
typedef __attribute__((ext_vector_type(8))) u16 u16x8;

#define N_IMG 64
#define C_IN  64
#define HW_IN 3136   // 56*56
#define W_IN  56
#define C_OUT 128
#define OH    54
#define OW    54
#define SPI   2916   // 54*54
#define KTOT  576    // C_IN*9
#define NBPI  23     // ceil(SPI/128) blocks per image
#define NWG   (N_IMG*NBPI)   // 1472 = 8*184
#define SLAB_POS 256 // slab rows (input positions), 32 KB

typedef __attribute__((address_space(3))) unsigned int lds_uint;
typedef __attribute__((address_space(1))) unsigned int gbl_uint;

__device__ __forceinline__ void load16_to_lds(const u16* g, u16* l) {
  // lane i of the wave writes LDS base + i*16 bytes; g is per-lane.
  __builtin_amdgcn_global_load_lds((const gbl_uint*)g, (lds_uint*)l, 16, 0, 0);
}

__device__ inline u16 f32_bf16_rne(float f) {
  unsigned u = __float_as_uint(f);
  u = (u + 0x7FFFu + ((u >> 16) & 1u)) >> 16;
  return (u16)u;
}

__device__ __forceinline__ bf16x8 as_bf16x8(f32x4 v) {
  union { f32x4 f; bf16x8 b; } u; u.f = v; return u.b;
}

// Merged converter (unchanged).
__global__ __launch_bounds__(256) void convert_xw(
    const float* __restrict__ x, const float* __restrict__ w,
    u16* __restrict__ xt, u16* __restrict__ wtT)
{
  if (blockIdx.y == N_IMG) {
    int o = blockIdx.x * 256 + threadIdx.x;
    for (; o < C_OUT * KTOT; o += 49 * 256) {
      int co = o / KTOT;
      int k  = o - co * KTOT;
      int t  = k >> 6;       // kh*3+kw
      int ci = k & 63;
      wtT[o] = f32_bf16_rne(w[co * KTOT + ci * 9 + t]);
    }
    return;
  }

  __shared__ u16 tile[64][68];
  int n  = blockIdx.y;
  int s0 = blockIdx.x * 64;
  int t  = threadIdx.x;

  int r = t >> 2;
  int q = t & 3;
  const float* xp = x + (size_t)n * C_IN * HW_IN + (size_t)r * HW_IN + s0 + q * 16;
  #pragma unroll
  for (int j = 0; j < 4; j++) {
    f32x4 v = *(const f32x4*)(xp + 4 * j);
    u16x4 o4;
    #pragma unroll
    for (int e = 0; e < 4; e++) {
      float f = fminf(fmaxf(v[e], -128.f), 127.f);
      int iv = (int)f;
      o4[e] = f32_bf16_rne((float)iv);
    }
    *(u16x4*)&tile[r][q * 16 + 4 * j] = o4;
  }
  __syncthreads();

  u16* op = xt + ((size_t)n * HW_IN + s0) * C_IN;
  int g = t & 7;
  int m = t >> 3;
  #pragma unroll
  for (int k2 = 0; k2 < 2; k2++) {
    int sp = m * 2 + k2;
    u16x8 o8;
    #pragma unroll
    for (int c = 0; c < 8; c++) o8[c] = tile[g * 8 + c][sp];
    *(u16x8*)&op[(size_t)sp * C_IN + g * 8] = o8;
  }
}

// Implicit GEMM: barrier-free, VMEM-free main loop.
// Pixels: 32 KB halo slab staged ONCE via global_load_lds (source-pre-swizzled),
//   one prologue __syncthreads, then read-only for all 9 taps.
// Weights: this wave's 32cout x 576k slice PRELOADED INTO 144 VGPRs before the
//   barrier (36 x global_load_dwordx4 from L2, issued back-to-back, drained by
//   the same vmcnt(0) the barrier needs). asm keep-alives pin the loads in the
//   prologue so regalloc cannot sink them into the loop (round-5 failure mode:
//   VGPR=60, per-MFMA exposed L2 latency, 79 us).
// Main loop: 72 ds_read_b128 + 144 MFMA per wave, ZERO barriers, ZERO VMEM ->
//   the regime where 2 waves/SIMD suffices (MFMA-only ubench hits 86% peak).
__global__ __launch_bounds__(512, 2) void conv_gemm(
    const u16* __restrict__ xt, const u16* __restrict__ wtT,
    const float* __restrict__ bias, float* __restrict__ y)
{
  __shared__ u16 slab[SLAB_POS * 64];   // 32 KB pixel slab (swizzled ci-groups)

  int tid  = threadIdx.x;
  int wv   = tid >> 6;           // 0..7
  int lane = tid & 63;
  int ln   = lane & 15;
  int q    = lane >> 4;
  int wy   = wv >> 1;            // cout quarter (32 rows)
  int wx   = wv & 1;             // spatial half (64 cols)

  // XCD-aware swizzle: 1472 = 8*184 exactly
  int b  = blockIdx.x;
  int wg = (b & 7) * (NWG / 8) + (b >> 3);
  int img = wg / NBPI;
  int cb  = wg - img * NBPI;
  int r0  = cb * 128;                    // first output position (image-local)
  int ibase = r0 + 2 * (r0 / OW);        // slab base input position

  const u16* xg = xt + ((size_t)img * HW_IN + ibase) * C_IN;

  // ---- slab staging: 4 rounds x 512 threads x 16 B = 32 KB ----
  // LDS written linearly; SOURCE carries the inverse swizzle so
  // LDS[row][colg] = xt[row][colg ^ (row&7)].
  #pragma unroll
  for (int j = 0; j < 4; j++) {
    int slot = j * 512 + tid;
    int row  = slot >> 3, cgc = slot & 7;
    int src  = row * 64 + ((cgc ^ (row & 7)) * 8);
    load16_to_lds(xg + src, slab + (size_t)(j * 512 + wv * 64) * 8);
  }

  // ---- W preload: 36 fragments = 144 VGPR, once per block ----
  const u16* wb0 = wtT + (size_t)(wy * 32 + ln) * KTOT + q * 8;
  const u16* wb1 = wb0 + (size_t)16 * KTOT;
  f32x4 wreg[9][2][2];
  #pragma unroll
  for (int kc = 0; kc < 9; kc++)
    #pragma unroll
    for (int s = 0; s < 2; s++) {
      wreg[kc][s][0] = *(const f32x4*)(wb0 + kc * 64 + s * 32);
      wreg[kc][s][1] = *(const f32x4*)(wb1 + kc * 64 + s * 32);
    }
  // pin the preload here: values must be materialized before the loop
  #pragma unroll
  for (int kc = 0; kc < 9; kc++)
    #pragma unroll
    for (int s = 0; s < 2; s++)
      asm volatile("" :: "v"(wreg[kc][s][0]), "v"(wreg[kc][s][1]));

  f32x4 acc[2][4];
  #pragma unroll
  for (int mt = 0; mt < 2; mt++)
    #pragma unroll
    for (int nt = 0; nt < 4; nt++)
      acc[mt][nt] = (f32x4){0.f, 0.f, 0.f, 0.f};

  // per-lane output positions and their slab base rows (tap (0,0))
  int prel[4], rbase[4];
  #pragma unroll
  for (int nt = 0; nt < 4; nt++) {
    int pr = r0 + wx * 64 + nt * 16 + ln;
    prel[nt]  = pr;
    rbase[nt] = pr + 2 * (pr / OW) - ibase;   // 0..133
  }

  __syncthreads();   // slab DMA + W loads drained (vmcnt(0)). ONLY barrier.

  #pragma unroll
  for (int kc = 0; kc < 9; kc++) {
    const int kh = kc / 3, kw = kc - kh * 3;
    const int koff = kh * W_IN + kw;         // slab row offset of this tap

    #pragma unroll
    for (int s = 0; s < 2; s++) {
      int gg = s * 4 + q;                    // ci 8-group within the tap
      bf16x8 pf[4];
      #pragma unroll
      for (int nt = 0; nt < 4; nt++) {
        int rb = rbase[nt] + koff;           // slab row for this lane+tap
        pf[nt] = *(const bf16x8*)(slab + rb * 64 + ((gg ^ (rb & 7)) * 8));
      }
      #pragma unroll
      for (int nt = 0; nt < 4; nt++)
        acc[0][nt] = __builtin_amdgcn_mfma_f32_16x16x32_bf16(
            as_bf16x8(wreg[kc][s][0]), pf[nt], acc[0][nt], 0, 0, 0);
      #pragma unroll
      for (int nt = 0; nt < 4; nt++)
        acc[1][nt] = __builtin_amdgcn_mfma_f32_16x16x32_bf16(
            as_bf16x8(wreg[kc][s][1]), pf[nt], acc[1][nt], 0, 0, 0);
    }
  }

  // epilogue: y is [img][co][p_rel]; mask the tail block's dead positions
  size_t obase0 = (size_t)img * C_OUT * SPI;
  #pragma unroll
  for (int nt = 0; nt < 4; nt++) {
    int pr = prel[nt];
    if (pr < SPI) {
      #pragma unroll
      for (int mt = 0; mt < 2; mt++) {
        int co0 = wy * 32 + mt * 16 + q * 4;
        #pragma unroll
        for (int r = 0; r < 4; r++)
          y[obase0 + (size_t)(co0 + r) * SPI + pr] = acc[mt][nt][r] + bias[co0 + r];
      }
    }
  }
}

extern "C" void kernel_launch(void* const* d_in, const int* in_sizes, int n_in,
                              void* d_out, int out_size, void* d_ws, size_t ws_size,
                              hipStream_t stream) {
  const float* x    = (const float*)d_in[0];
  const float* w    = (const float*)d_in[1];
  const float* bias = (const float*)d_in[2];
  float* y = (float*)d_out;

  u16* wtT = (u16*)d_ws;
  u16* xt  = (u16*)((char*)d_ws + (size_t)C_OUT * KTOT * sizeof(u16)); // +147456 B

  hipLaunchKernelGGL(convert_xw, dim3(HW_IN / 64, N_IMG + 1), dim3(256), 0, stream,
                     x, w, xt, wtT);
  hipLaunchKernelGGL(conv_gemm, dim3(NWG), dim3(512), 0, stream,
                     xt, wtT, bias, y);
}

// Round 7
// 165.905 us; speedup vs baseline: 1.2430x; 1.2430x over previous
//
#include <hip/hip_runtime.h>
#include <stdint.h>

typedef unsigned short u16;
typedef __attribute__((ext_vector_type(8))) __bf16 bf16x8;
typedef __attribute__((ext_vector_type(4))) float f32x4;
typedef __attribute__((ext_vector_type(4))) u16 u16x4;
typedef __attribute__((ext_vector_type(8))) u16 u16x8;

#define N_IMG 64
#define C_IN  64
#define HW_IN 3136   // 56*56
#define W_IN  56
#define C_OUT 128
#define OH    54
#define OW    54
#define SPI   2916   // 54*54
#define KTOT  576    // C_IN*9
#define SP_BLK 192   // output positions per block
#define NBPI  16     // ceil(SPI/192)
#define NWG   (N_IMG*NBPI)   // 1024 = 8*128
#define SLAB_ROWS 320 // max needed: 199 (intra-block span) + 114 (tap) = 313

typedef __attribute__((address_space(3))) unsigned int lds_uint;
typedef __attribute__((address_space(1))) unsigned int gbl_uint;

__device__ __forceinline__ void load16_to_lds(const u16* g, u16* l) {
  // lane i of the wave writes LDS base + i*16 bytes; g is per-lane.
  __builtin_amdgcn_global_load_lds((const gbl_uint*)g, (lds_uint*)l, 16, 0, 0);
}

__device__ inline u16 f32_bf16_rne(float f) {
  unsigned u = __float_as_uint(f);
  u = (u + 0x7FFFu + ((u >> 16) & 1u)) >> 16;
  return (u16)u;
}

// Merged converter (unchanged).
__global__ __launch_bounds__(256) void convert_xw(
    const float* __restrict__ x, const float* __restrict__ w,
    u16* __restrict__ xt, u16* __restrict__ wtT)
{
  if (blockIdx.y == N_IMG) {
    int o = blockIdx.x * 256 + threadIdx.x;
    for (; o < C_OUT * KTOT; o += 49 * 256) {
      int co = o / KTOT;
      int k  = o - co * KTOT;
      int t  = k >> 6;       // kh*3+kw
      int ci = k & 63;
      wtT[o] = f32_bf16_rne(w[co * KTOT + ci * 9 + t]);
    }
    return;
  }

  __shared__ u16 tile[64][68];
  int n  = blockIdx.y;
  int s0 = blockIdx.x * 64;
  int t  = threadIdx.x;

  int r = t >> 2;
  int q = t & 3;
  const float* xp = x + (size_t)n * C_IN * HW_IN + (size_t)r * HW_IN + s0 + q * 16;
  #pragma unroll
  for (int j = 0; j < 4; j++) {
    f32x4 v = *(const f32x4*)(xp + 4 * j);
    u16x4 o4;
    #pragma unroll
    for (int e = 0; e < 4; e++) {
      float f = fminf(fmaxf(v[e], -128.f), 127.f);
      int iv = (int)f;
      o4[e] = f32_bf16_rne((float)iv);
    }
    *(u16x4*)&tile[r][q * 16 + 4 * j] = o4;
  }
  __syncthreads();

  u16* op = xt + ((size_t)n * HW_IN + s0) * C_IN;
  int g = t & 7;
  int m = t >> 3;
  #pragma unroll
  for (int k2 = 0; k2 < 2; k2++) {
    int sp = m * 2 + k2;
    u16x8 o8;
    #pragma unroll
    for (int c = 0; c < 8; c++) o8[c] = tile[g * 8 + c][sp];
    *(u16x8*)&op[(size_t)sp * C_IN + g * 8] = o8;
  }
}

// Implicit GEMM, WIDE-WAVE-TILE variant (round-3 skeleton, fewer LDS reads).
// Block = 192 spatial x 128 cout of ONE image, 4 waves (256 thr),
// wave tile = 64 cout x 96 sp -> acc[4][6] (96 VGPR).
// Per tap per wave: 20 ds_read_b128 + 48 MFMA (round-3: 12 reads / 16 MFMA) ->
// reads/MFMA 0.75 -> 0.42, 4x longer barrier phases, 36 (vs 51) drains/CU.
// Pixels: 40 KB halo slab staged ONCE (all 9 taps are just row offsets).
// Weights: 2x16 KB LDS dbuf, tap kc+1 prefetched via global_load_lds right
// after the barrier, draining at the NEXT barrier (VMEM never exposed in the
// compute path - rounds 5/6 proved the compiler won't pipeline inner-loop VMEM).
// LDS total 72 KB -> 2 blocks/CU co-resident (cross-block overlap of drains).
__global__ __launch_bounds__(256, 2) void conv_gemm(
    const u16* __restrict__ xt, const u16* __restrict__ wtT,
    const float* __restrict__ bias, float* __restrict__ y)
{
  __shared__ u16 slab[SLAB_ROWS * 64];  // 40 KB pixel slab (swizzled ci-groups)
  __shared__ u16 sW[2][128 * 64];       // 32 KB weight dbuf

  int tid  = threadIdx.x;
  int wv   = tid >> 6;           // 0..3
  int lane = tid & 63;
  int ln   = lane & 15;
  int q    = lane >> 4;
  int wy   = wv >> 1;            // cout half (64 rows)
  int wx   = wv & 1;             // spatial half (96 cols)

  // XCD-aware swizzle: 1024 = 8*128 exactly
  int b  = blockIdx.x;
  int wg = (b & 7) * (NWG / 8) + (b >> 3);
  int img = wg >> 4;                     // wg / NBPI
  int cb  = wg & 15;
  int r0  = cb * SP_BLK;                 // first output position (image-local)
  int ibase = r0 + 2 * (r0 / OW);        // slab base input position

  const u16* xti = xt + (size_t)img * HW_IN * C_IN;

  // staging lane mapping: slot = j*256 + tid -> row = j*32 + (tid>>3), group tid&7
  int trow = tid >> 3;           // 0..31
  int cg   = tid & 7;

  // ---- slab staging: 10 rounds x 256 thr x 16 B = 40 KB, source-pre-swizzled;
  //      rows past the image end are clamped (garbage feeds only dead outputs).
  #pragma unroll
  for (int j = 0; j < 10; j++) {
    int row  = j * 32 + trow;
    int grow = ibase + row;
    if (grow > HW_IN - 1) grow = HW_IN - 1;
    load16_to_lds(xti + (size_t)grow * 64 + ((cg ^ (row & 7)) * 8),
                  slab + (size_t)(j * 256 + wv * 64) * 8);
  }

  // ---- W staging bases; tap t adds t*64 ----
  int wt_base[4];
  #pragma unroll
  for (int j = 0; j < 4; j++) {
    int row = j * 32 + trow;                   // cout row 0..127
    wt_base[j] = row * KTOT + ((cg ^ (row & 7)) * 8);
  }
  // prologue: W tap 0 into buf 0
  #pragma unroll
  for (int j = 0; j < 4; j++)
    load16_to_lds(wtT + wt_base[j], &sW[0][(j * 256 + wv * 64) * 8]);

  f32x4 acc[4][6];
  #pragma unroll
  for (int mt = 0; mt < 4; mt++)
    #pragma unroll
    for (int nt = 0; nt < 6; nt++)
      acc[mt][nt] = (f32x4){0.f, 0.f, 0.f, 0.f};

  // per-lane output positions and slab base rows (tap (0,0))
  int prel[6], rbase[6];
  #pragma unroll
  for (int nt = 0; nt < 6; nt++) {
    int pr = r0 + wx * 96 + nt * 16 + ln;
    prel[nt]  = pr;
    rbase[nt] = pr + 2 * (pr / OW) - ibase;    // 0..199
  }
  // W-fragment row bases
  int wrow[4];
  #pragma unroll
  for (int mt = 0; mt < 4; mt++) wrow[mt] = wy * 64 + mt * 16 + ln;   // cout row

  #pragma unroll
  for (int kc = 0; kc < 9; kc++) {
    const int cur = kc & 1, nxt = cur ^ 1;
    const int kh = kc / 3, kw = kc - kh * 3;
    const int koff = kh * W_IN + kw;           // slab row offset of this tap

    // drains vmcnt(0)+lgkmcnt(0): W[cur] (+slab on kc==0) landed for all
    // waves; everyone's reads of sW[nxt] (last iter's cur) retired.
    __syncthreads();

    if (kc < 8) {   // prefetch next tap's weights; flies during the MFMA below
      #pragma unroll
      for (int j = 0; j < 4; j++)
        load16_to_lds(wtT + wt_base[j] + (kc + 1) * 64,
                      &sW[nxt][(j * 256 + wv * 64) * 8]);
    }

    #pragma unroll
    for (int s = 0; s < 2; s++) {
      int gg = s * 4 + q;                      // ci 8-group within the tap
      bf16x8 wf[4], pf[6];
      #pragma unroll
      for (int mt = 0; mt < 4; mt++) {
        int co = wrow[mt];
        wf[mt] = *(const bf16x8*)(&sW[cur][0] + co * 64 + ((gg ^ (co & 7)) * 8));
      }
      #pragma unroll
      for (int nt = 0; nt < 6; nt++) {
        int rb = rbase[nt] + koff;             // slab row for this lane+tap
        pf[nt] = *(const bf16x8*)(slab + rb * 64 + ((gg ^ (rb & 7)) * 8));
      }
      #pragma unroll
      for (int mt = 0; mt < 4; mt++)
        #pragma unroll
        for (int nt = 0; nt < 6; nt++)
          acc[mt][nt] = __builtin_amdgcn_mfma_f32_16x16x32_bf16(
              wf[mt], pf[nt], acc[mt][nt], 0, 0, 0);
    }
  }

  // epilogue: y is [img][co][p_rel]; mask dead tail positions
  size_t obase0 = (size_t)img * C_OUT * SPI;
  #pragma unroll
  for (int nt = 0; nt < 6; nt++) {
    int pr = prel[nt];
    if (pr < SPI) {
      #pragma unroll
      for (int mt = 0; mt < 4; mt++) {
        int co0 = wy * 64 + mt * 16 + q * 4;
        #pragma unroll
        for (int r = 0; r < 4; r++)
          y[obase0 + (size_t)(co0 + r) * SPI + pr] = acc[mt][nt][r] + bias[co0 + r];
      }
    }
  }
}

extern "C" void kernel_launch(void* const* d_in, const int* in_sizes, int n_in,
                              void* d_out, int out_size, void* d_ws, size_t ws_size,
                              hipStream_t stream) {
  const float* x    = (const float*)d_in[0];
  const float* w    = (const float*)d_in[1];
  const float* bias = (const float*)d_in[2];
  float* y = (float*)d_out;

  u16* wtT = (u16*)d_ws;
  u16* xt  = (u16*)((char*)d_ws + (size_t)C_OUT * KTOT * sizeof(u16)); // +147456 B

  hipLaunchKernelGGL(convert_xw, dim3(HW_IN / 64, N_IMG + 1), dim3(256), 0, stream,
                     x, w, xt, wtT);
  hipLaunchKernelGGL(conv_gemm, dim3(NWG), dim3(256), 0, stream,
                     xt, wtT, bias, y);
}

// Round 8
// 164.474 us; speedup vs baseline: 1.2538x; 1.0087x over previous
//
#include <hip/hip_runtime.h>
#include <stdint.h>

typedef unsigned short u16;
typedef __attribute__((ext_vector_type(8))) __bf16 bf16x8;
typedef __attribute__((ext_vector_type(4))) float f32x4;
typedef __attribute__((ext_vector_type(4))) u16 u16x4;
typedef __attribute__((ext_vector_type(8))) u16 u16x8;

#define N_IMG 64
#define C_IN  64
#define HW_IN 3136   // 56*56
#define W_IN  56
#define C_OUT 128
#define OH    54
#define OW    54
#define SPI   2916   // 54*54
#define KTOT  576    // C_IN*9
#define SP_BLK 192   // output positions per block
#define NBPI  16     // ceil(SPI/192)
#define NWG   (N_IMG*NBPI)   // 1024 = 8*128
#define SLAB_ROWS 320 // max needed: 199 (intra-block span) + 114 (tap) = 313

typedef __attribute__((address_space(3))) unsigned int lds_uint;
typedef __attribute__((address_space(1))) unsigned int gbl_uint;

__device__ __forceinline__ void load16_to_lds(const u16* g, u16* l) {
  // lane i of the wave writes LDS base + i*16 bytes; g is per-lane.
  __builtin_amdgcn_global_load_lds((const gbl_uint*)g, (lds_uint*)l, 16, 0, 0);
}

__device__ inline u16 f32_bf16_rne(float f) {
  unsigned u = __float_as_uint(f);
  u = (u + 0x7FFFu + ((u >> 16) & 1u)) >> 16;
  return (u16)u;
}

// Merged converter (unchanged).
__global__ __launch_bounds__(256) void convert_xw(
    const float* __restrict__ x, const float* __restrict__ w,
    u16* __restrict__ xt, u16* __restrict__ wtT)
{
  if (blockIdx.y == N_IMG) {
    int o = blockIdx.x * 256 + threadIdx.x;
    for (; o < C_OUT * KTOT; o += 49 * 256) {
      int co = o / KTOT;
      int k  = o - co * KTOT;
      int t  = k >> 6;       // kh*3+kw
      int ci = k & 63;
      wtT[o] = f32_bf16_rne(w[co * KTOT + ci * 9 + t]);
    }
    return;
  }

  __shared__ u16 tile[64][68];
  int n  = blockIdx.y;
  int s0 = blockIdx.x * 64;
  int t  = threadIdx.x;

  int r = t >> 2;
  int q = t & 3;
  const float* xp = x + (size_t)n * C_IN * HW_IN + (size_t)r * HW_IN + s0 + q * 16;
  #pragma unroll
  for (int j = 0; j < 4; j++) {
    f32x4 v = *(const f32x4*)(xp + 4 * j);
    u16x4 o4;
    #pragma unroll
    for (int e = 0; e < 4; e++) {
      float f = fminf(fmaxf(v[e], -128.f), 127.f);
      int iv = (int)f;
      o4[e] = f32_bf16_rne((float)iv);
    }
    *(u16x4*)&tile[r][q * 16 + 4 * j] = o4;
  }
  __syncthreads();

  u16* op = xt + ((size_t)n * HW_IN + s0) * C_IN;
  int g = t & 7;
  int m = t >> 3;
  #pragma unroll
  for (int k2 = 0; k2 < 2; k2++) {
    int sp = m * 2 + k2;
    u16x8 o8;
    #pragma unroll
    for (int c = 0; c < 8; c++) o8[c] = tile[g * 8 + c][sp];
    *(u16x8*)&op[(size_t)sp * C_IN + g * 8] = o8;
  }
}

// Implicit GEMM, wide-wave-tile + WAVE-STAGGERED phases.
// Block = 192 spatial x 128 cout of ONE image, 4 waves, wave tile 64co x 96sp.
// Pixels: 40 KB halo slab staged ONCE; weights: 2x16 KB LDS dbuf, prefetched
// one tap ahead. 72 KB LDS -> 2 blocks/CU.
// Round-8 changes (anti-lockstep; rounds 2/3/7 all ~46-49 us regardless of
// geometry because all waves flood the LDS pipe together after each barrier,
// then burst MFMA together):
//  1. wave wv computes k-half (wv&1) FIRST -> half the waves read while the
//     other half MFMA (producer/consumer role split inside each tap phase).
//  2. s_setprio(1) around MFMA clusters (T5 - pays once roles are split).
//  3. W-prefetch issued between the two k-half sub-phases (off the
//     post-barrier read flood, still ~a full phase of slack to land).
__global__ __launch_bounds__(256, 2) void conv_gemm(
    const u16* __restrict__ xt, const u16* __restrict__ wtT,
    const float* __restrict__ bias, float* __restrict__ y)
{
  __shared__ u16 slab[SLAB_ROWS * 64];  // 40 KB pixel slab (swizzled ci-groups)
  __shared__ u16 sW[2][128 * 64];       // 32 KB weight dbuf

  int tid  = threadIdx.x;
  int wv   = tid >> 6;           // 0..3
  int lane = tid & 63;
  int ln   = lane & 15;
  int q    = lane >> 4;
  int wy   = wv >> 1;            // cout half (64 rows)
  int wx   = wv & 1;             // spatial half (96 cols)

  // XCD-aware swizzle: 1024 = 8*128 exactly
  int b  = blockIdx.x;
  int wg = (b & 7) * (NWG / 8) + (b >> 3);
  int img = wg >> 4;                     // wg / NBPI
  int cb  = wg & 15;
  int r0  = cb * SP_BLK;                 // first output position (image-local)
  int ibase = r0 + 2 * (r0 / OW);        // slab base input position

  const u16* xti = xt + (size_t)img * HW_IN * C_IN;

  // staging lane mapping: slot = j*256 + tid -> row = j*32 + (tid>>3), group tid&7
  int trow = tid >> 3;           // 0..31
  int cg   = tid & 7;

  // ---- slab staging: 10 rounds x 256 thr x 16 B = 40 KB, source-pre-swizzled;
  //      rows past the image end are clamped (garbage feeds only dead outputs).
  #pragma unroll
  for (int j = 0; j < 10; j++) {
    int row  = j * 32 + trow;
    int grow = ibase + row;
    if (grow > HW_IN - 1) grow = HW_IN - 1;
    load16_to_lds(xti + (size_t)grow * 64 + ((cg ^ (row & 7)) * 8),
                  slab + (size_t)(j * 256 + wv * 64) * 8);
  }

  // ---- W staging bases; tap t adds t*64 ----
  int wt_base[4];
  #pragma unroll
  for (int j = 0; j < 4; j++) {
    int row = j * 32 + trow;                   // cout row 0..127
    wt_base[j] = row * KTOT + ((cg ^ (row & 7)) * 8);
  }
  // prologue: W tap 0 into buf 0
  #pragma unroll
  for (int j = 0; j < 4; j++)
    load16_to_lds(wtT + wt_base[j], &sW[0][(j * 256 + wv * 64) * 8]);

  f32x4 acc[4][6];
  #pragma unroll
  for (int mt = 0; mt < 4; mt++)
    #pragma unroll
    for (int nt = 0; nt < 6; nt++)
      acc[mt][nt] = (f32x4){0.f, 0.f, 0.f, 0.f};

  // per-lane output positions and slab base rows (tap (0,0))
  int prel[6], rbase[6];
  #pragma unroll
  for (int nt = 0; nt < 6; nt++) {
    int pr = r0 + wx * 96 + nt * 16 + ln;
    prel[nt]  = pr;
    rbase[nt] = pr + 2 * (pr / OW) - ibase;    // 0..199
  }
  // W-fragment row bases
  int wrow[4];
  #pragma unroll
  for (int mt = 0; mt < 4; mt++) wrow[mt] = wy * 64 + mt * 16 + ln;   // cout row

  int shalf = wv & 1;            // this wave's FIRST k-half (stagger)

  #pragma unroll
  for (int kc = 0; kc < 9; kc++) {
    const int cur = kc & 1, nxt = cur ^ 1;
    const int kh = kc / 3, kw = kc - kh * 3;
    const int koff = kh * W_IN + kw;           // slab row offset of this tap

    // drains vmcnt(0)+lgkmcnt(0): W[cur] (+slab on kc==0) landed for all
    // waves; everyone's reads of sW[nxt] (last iter's cur) retired.
    __syncthreads();

    #pragma unroll
    for (int si = 0; si < 2; si++) {
      int gg = (si ^ shalf) * 4 + q;           // staggered ci 8-group
      bf16x8 wf[4], pf[6];
      #pragma unroll
      for (int mt = 0; mt < 4; mt++) {
        int co = wrow[mt];
        wf[mt] = *(const bf16x8*)(&sW[cur][0] + co * 64 + ((gg ^ (co & 7)) * 8));
      }
      #pragma unroll
      for (int nt = 0; nt < 6; nt++) {
        int rb = rbase[nt] + koff;             // slab row for this lane+tap
        pf[nt] = *(const bf16x8*)(slab + rb * 64 + ((gg ^ (rb & 7)) * 8));
      }

      // W-prefetch for tap kc+1: issued between the two sub-phases, off the
      // post-barrier read flood. Safe: sW[nxt] reads retired at the barrier.
      if (si == 0 && kc < 8) {
        #pragma unroll
        for (int j = 0; j < 4; j++)
          load16_to_lds(wtT + wt_base[j] + (kc + 1) * 64,
                        &sW[nxt][(j * 256 + wv * 64) * 8]);
      }

      __builtin_amdgcn_s_setprio(1);
      #pragma unroll
      for (int mt = 0; mt < 4; mt++)
        #pragma unroll
        for (int nt = 0; nt < 6; nt++)
          acc[mt][nt] = __builtin_amdgcn_mfma_f32_16x16x32_bf16(
              wf[mt], pf[nt], acc[mt][nt], 0, 0, 0);
      __builtin_amdgcn_s_setprio(0);
    }
  }

  // epilogue: y is [img][co][p_rel]; mask dead tail positions
  size_t obase0 = (size_t)img * C_OUT * SPI;
  #pragma unroll
  for (int nt = 0; nt < 6; nt++) {
    int pr = prel[nt];
    if (pr < SPI) {
      #pragma unroll
      for (int mt = 0; mt < 4; mt++) {
        int co0 = wy * 64 + mt * 16 + q * 4;
        #pragma unroll
        for (int r = 0; r < 4; r++)
          y[obase0 + (size_t)(co0 + r) * SPI + pr] = acc[mt][nt][r] + bias[co0 + r];
      }
    }
  }
}

extern "C" void kernel_launch(void* const* d_in, const int* in_sizes, int n_in,
                              void* d_out, int out_size, void* d_ws, size_t ws_size,
                              hipStream_t stream) {
  const float* x    = (const float*)d_in[0];
  const float* w    = (const float*)d_in[1];
  const float* bias = (const float*)d_in[2];
  float* y = (float*)d_out;

  u16* wtT = (u16*)d_ws;
  u16* xt  = (u16*)((char*)d_ws + (size_t)C_OUT * KTOT * sizeof(u16)); // +147456 B

  hipLaunchKernelGGL(convert_xw, dim3(HW_IN / 64, N_IMG + 1), dim3(256), 0, stream,
                     x, w, xt, wtT);
  hipLaunchKernelGGL(conv_gemm, dim3(NWG), dim3(256), 0, stream,
                     xt, wtT, bias, y);
}